// Round 8
// baseline (246.539 us; speedup 1.0000x reference)
//
#include <hip/hip_runtime.h>
#include <hip/hip_bf16.h>
#include <stdint.h>

// ---- types ----
typedef __attribute__((ext_vector_type(4))) int i32x4;   // 16 i8 MFMA frag / i32x4 accum

// ---- problem sizes ----
#define NIMG 32
#define CIN  256
#define HWDIM 56
#define HPAD 58
#define OCH  256
#define SPATIAL (HWDIM*HWDIM)        // 3136
#define M_TOT (NIMG*SPATIAL)         // 100352
#define KTOT  2304                    // 9*256
#define NSTEP 36                      // K-steps of 64 i8

// workspace layout (bytes)
#define WT_OFF     27557888ull        // after xb: 32*58*58*256 i8
#define ALPHA_OFF  28147712ull        // after WT: 256*2304 i8

// =====================================================================
// Kernel 1: per-o alpha + ternary i8 weights transposed to WT[o][k], k = tap*256 + c
// =====================================================================
__global__ __launch_bounds__(256)
void prep_weights(const float* __restrict__ w1, const float* __restrict__ w2,
                  char* __restrict__ WT, float* __restrict__ alpha) {
    const int o = blockIdx.x;
    const int t = threadIdx.x;
    const float* p1 = w1 + o * KTOT;
    const float* p2 = w2 + o * KTOT;
    char* wo = WT + o * KTOT;

    float s1 = 0.f, s2 = 0.f;
    for (int i = t; i < KTOT; i += 256) {
        float a = p1[i], b = p2[i];
        s1 += fabsf(a);
        s2 += fabsf(b);
        int sg = ((a > 0.f) ? 1 : ((a < 0.f) ? -1 : 0))
               + ((b > 0.f) ? 1 : ((b < 0.f) ? -1 : 0));
        int c = i / 9;
        int tap = i - c * 9;
        wo[tap * 256 + c] = (char)sg;
    }
    __shared__ float red[8];
    #pragma unroll
    for (int off = 32; off > 0; off >>= 1) {
        s1 += __shfl_down(s1, off, 64);
        s2 += __shfl_down(s2, off, 64);
    }
    const int lane = t & 63, wv = t >> 6;
    if (lane == 0) { red[wv] = s1; red[4 + wv] = s2; }
    __syncthreads();
    if (t == 0) {
        float t1 = red[0] + red[1] + red[2] + red[3];
        float t2 = red[4] + red[5] + red[6] + red[7];
        alpha[o] = (t1 * (1.f / 2304.f) + t2 * (1.f / 2304.f)) * 0.5f;
    }
}

// =====================================================================
// Kernel 2: binarize + NCHW -> padded NHWC i8, including border zeroing.
// Grid = 32 * 58 blocks: one per (n, hp).
// =====================================================================
__global__ __launch_bounds__(256)
void binarize_kernel(const float* __restrict__ x, char* __restrict__ xb) {
    const int b  = blockIdx.x;
    const int n  = b / HPAD;
    const int hp = b % HPAD;
    const int t  = threadIdx.x;
    char* rowp = xb + ((size_t)n * HPAD + hp) * (HPAD * CIN);

    if (hp == 0 || hp == HPAD - 1) {
        int* ip = (int*)rowp;                 // 58*256 B = 3712 ints
        for (int i = t; i < 3712; i += 256) ip[i] = 0;
        return;
    }
    const int h = hp - 1;
    __shared__ __align__(4) char tile[HWDIM * 260];
    if (t < 224) {
        const int w  = t % HWDIM;
        const int cl = t / HWDIM;
        const float* xp = x + (size_t)n * (CIN * SPATIAL) + (size_t)h * HWDIM + w;
        for (int c0 = 0; c0 < CIN; c0 += 4) {
            int c = c0 + cl;
            float v = xp[(size_t)c * SPATIAL];
            tile[w * 260 + c] = (v > 0.f) ? 1 : ((v < 0.f) ? -1 : 0);
        }
    }
    // zero left/right pad columns of this row
    int* ip = (int*)rowp;
    if (t < 64) ip[t] = 0;                    // w = 0
    else if (t < 128) ip[3648 + (t - 64)] = 0;// w = 57
    __syncthreads();
    const int wv = t >> 6, lane = t & 63;
    char* op = rowp + CIN;                    // w starts at 1
    for (int w0 = 0; w0 < HWDIM; w0 += 4) {
        int w = w0 + wv;
        int val = *(const int*)&tile[w * 260 + lane * 4];
        *(int*)(op + (size_t)w * CIN + lane * 4) = val;
    }
}

// =====================================================================
// Kernel 3: i8 implicit-GEMM, LDS-FREE. Block = 128(o) x 256(sp), 4 waves
// of 128x64 (acc[8][4]). Both MFMA operands loaded per-lane from global
// through L1/L2 (WT 576KB and the block's xb slice are cache-resident;
// all 4 waves share the same per-step 8KB W slice -> L1 hits).
// No LDS, no barriers, no inline asm: every wait compiler-inserted.
// This removes the r3-r5 LDS-BW wall (144KB/CU-pair-step > MFMA time)
// and the r7 mixed-counter correctness hazard.
// =====================================================================
__global__ __launch_bounds__(256, 2)
void conv_kernel(const char* __restrict__ xb,
                 const char* __restrict__ WT,
                 const float* __restrict__ alpha,
                 float* __restrict__ out) {
    const int t    = threadIdx.x;
    const int lane = t & 63;
    const int wv   = t >> 6;

    // XCD-aware bijective remap: 784 blocks = 8 XCDs * 98
    const int bid  = blockIdx.x;
    const int tid_ = (bid & 7) * 98 + (bid >> 3);
    const int nt   = tid_ & 1;        // o-tile (0/1)
    const int mt   = tid_ >> 1;       // sp-tile (0..391)
    const int o0   = nt * 128;
    const int m0   = mt * 256;

    const int rl = lane & 15;         // fragment row within 16
    const int kq = (lane >> 4) * 16;  // lane's 16-byte k-slice

    // ---- per-lane W row pointers (8 o-frags); step s adds s*64 (imm-foldable)
    const char* wb[8];
    #pragma unroll
    for (int i = 0; i < 8; ++i)
        wb[i] = WT + (size_t)(o0 + i * 16 + rl) * KTOT + kq;

    // ---- per-lane A row pointers (4 sp-frags)
    const char* ab[4];
    #pragma unroll
    for (int j = 0; j < 4; ++j) {
        int m  = m0 + wv * 64 + j * 16 + rl;
        int ni = m / SPATIAL;
        int sp = m - ni * SPATIAL;
        int h  = sp / HWDIM;
        int w  = sp - h * HWDIM;
        ab[j] = xb + ((size_t)(ni * HPAD + h) * HPAD + w) * CIN + kq;
    }

    i32x4 acc[8][4];
    #pragma unroll
    for (int i = 0; i < 8; ++i)
        #pragma unroll
        for (int j = 0; j < 4; ++j)
            acc[i][j] = (i32x4){0, 0, 0, 0};

    i32x4 xf[2][4];     // A fragments, parity double-buffered

    #define LOAD_A(S, P)                                                    \
    {                                                                       \
        const int s_ = (S);                                                 \
        const int tap = s_ >> 2;                                            \
        const int kh = tap / 3, kw = tap - kh * 3;                          \
        const int aoff = (kh * HPAD + kw) * CIN + (s_ & 3) * 64;            \
        xf[P][0] = *(const i32x4*)(ab[0] + aoff);                           \
        xf[P][1] = *(const i32x4*)(ab[1] + aoff);                           \
        xf[P][2] = *(const i32x4*)(ab[2] + aoff);                           \
        xf[P][3] = *(const i32x4*)(ab[3] + aoff);                           \
    }

    LOAD_A(0, 0);

    #pragma unroll
    for (int s = 0; s < NSTEP; ++s) {
        const int p = s & 1;

        if (s + 1 < NSTEP) LOAD_A(s + 1, p ^ 1);   // prefetch next A

        i32x4 wf[8];
        #pragma unroll
        for (int i = 0; i < 8; ++i)
            wf[i] = *(const i32x4*)(wb[i] + s * 64);

        #pragma unroll
        for (int i = 0; i < 8; ++i)
            #pragma unroll
            for (int j = 0; j < 4; ++j)
                acc[i][j] = __builtin_amdgcn_mfma_i32_16x16x64_i8(
                    wf[i], xf[p][j], acc[i][j], 0, 0, 0);
    }
    #undef LOAD_A

    // ---- epilogue: out[n][o][h][w] = acc * alpha[o] ----
    // D frag: col(sp) = lane&15, row(o) = (lane>>4)*4 + reg
    #pragma unroll
    for (int i = 0; i < 8; ++i) {
        const int ob = o0 + i * 16 + (lane >> 4) * 4;
        float al[4];
        #pragma unroll
        for (int r = 0; r < 4; ++r) al[r] = alpha[ob + r];
        #pragma unroll
        for (int j = 0; j < 4; ++j) {
            int m  = m0 + wv * 64 + j * 16 + rl;
            int ni = m / SPATIAL;
            int sp = m - ni * SPATIAL;
            long base = (long)ni * (OCH * SPATIAL) + sp;
            #pragma unroll
            for (int r = 0; r < 4; ++r) {
                out[base + (long)(ob + r) * SPATIAL] = (float)acc[i][j][r] * al[r];
            }
        }
    }
}

// =====================================================================
extern "C" void kernel_launch(void* const* d_in, const int* in_sizes, int n_in,
                              void* d_out, int out_size, void* d_ws, size_t ws_size,
                              hipStream_t stream) {
    const float* x  = (const float*)d_in[0];
    const float* w1 = (const float*)d_in[1];
    const float* w2 = (const float*)d_in[2];
    float* out = (float*)d_out;

    char* ws = (char*)d_ws;
    char*  xb    = ws;
    char*  WT    = ws + WT_OFF;
    float* alpha = (float*)(ws + ALPHA_OFF);

    hipLaunchKernelGGL(prep_weights, dim3(OCH), dim3(256), 0, stream, w1, w2, WT, alpha);
    hipLaunchKernelGGL(binarize_kernel, dim3(NIMG * HPAD), dim3(256), 0, stream, x, xb);
    hipLaunchKernelGGL(conv_kernel, dim3(M_TOT / 128), dim3(256), 0, stream,
                       xb, WT, alpha, out);
}

// Round 9
// 97.359 us; speedup vs baseline: 2.5323x; 2.5323x over previous
//
#include <hip/hip_runtime.h>
#include <hip/hip_bf16.h>
#include <stdint.h>

// ---- types ----
typedef __attribute__((ext_vector_type(4)))  int   i32x4;
typedef __attribute__((ext_vector_type(8)))  int   i32x8;
typedef __attribute__((ext_vector_type(16))) float f32x16;

typedef const void __attribute__((address_space(1)))* gas_ptr;
typedef void __attribute__((address_space(3)))* las_ptr;
#define GLD16(g, l) __builtin_amdgcn_global_load_lds((gas_ptr)(g), (las_ptr)(l), 16, 0, 0)

// ---- problem sizes ----
#define NIMG 32
#define CIN  256
#define HWDIM 56
#define HPAD 58
#define OCH  256
#define SPATIAL (HWDIM*HWDIM)        // 3136
#define M_TOT (NIMG*SPATIAL)         // 100352
#define KTOT  2304                    // 9*256
#define NSTEP 36                      // K-steps of 64 (fp4 nibbles)
#define ROWB  128                     // bytes per padded spatial position (256c/2)
#define WROWB 1152                    // bytes per o-row of WT4 (2304 nibbles)

// workspace layout (bytes)
#define WT4_OFF   13778944ull         // after xb4: 32*58*58*128
#define ALPHA_OFF 14073856ull         // after WT4: 256*1152

#define LDSBUF 12288                  // W 128x32B (4KB) + A 256x32B (8KB)

// =====================================================================
// Kernel 1: per-o alpha + ternary fp4(e2m1) weights, transposed+packed:
// WT4[o][byte i] = nibbles for k=2i (low), k=2i+1 (high); k = tap*256 + c
// =====================================================================
__global__ __launch_bounds__(256)
void prep_weights(const float* __restrict__ w1, const float* __restrict__ w2,
                  unsigned char* __restrict__ WT4, float* __restrict__ alpha) {
    const int o = blockIdx.x;
    const int t = threadIdx.x;
    const float* p1 = w1 + o * KTOT;
    const float* p2 = w2 + o * KTOT;
    unsigned char* wo = WT4 + o * WROWB;

    float s1 = 0.f, s2 = 0.f;
    for (int i = t; i < WROWB; i += 256) {
        int k0  = 2 * i;
        int tap = k0 >> 8;            // k = tap*256 + c
        int c   = k0 & 255;           // even
        float a0 = p1[c * 9 + tap],       b0 = p2[c * 9 + tap];
        float a1 = p1[(c + 1) * 9 + tap], b1 = p2[(c + 1) * 9 + tap];
        s1 += fabsf(a0) + fabsf(a1);
        s2 += fabsf(b0) + fabsf(b1);
        int sg0 = ((a0 > 0.f) - (a0 < 0.f)) + ((b0 > 0.f) - (b0 < 0.f));
        int sg1 = ((a1 > 0.f) - (a1 < 0.f)) + ((b1 > 0.f) - (b1 < 0.f));
        // fp4 e2m1: +1=0x2 +2=0x4 -1=0xA -2=0xC 0=0x0
        unsigned e0 = (sg0 == 2) ? 0x4u : (sg0 == 1) ? 0x2u : (sg0 == 0) ? 0x0u
                    : (sg0 == -1) ? 0xAu : 0xCu;
        unsigned e1 = (sg1 == 2) ? 0x4u : (sg1 == 1) ? 0x2u : (sg1 == 0) ? 0x0u
                    : (sg1 == -1) ? 0xAu : 0xCu;
        wo[i] = (unsigned char)(e0 | (e1 << 4));
    }
    __shared__ float red[8];
    #pragma unroll
    for (int off = 32; off > 0; off >>= 1) {
        s1 += __shfl_down(s1, off, 64);
        s2 += __shfl_down(s2, off, 64);
    }
    const int lane = t & 63, wv = t >> 6;
    if (lane == 0) { red[wv] = s1; red[4 + wv] = s2; }
    __syncthreads();
    if (t == 0) {
        float t1 = red[0] + red[1] + red[2] + red[3];
        float t2 = red[4] + red[5] + red[6] + red[7];
        alpha[o] = (t1 * (1.f / 2304.f) + t2 * (1.f / 2304.f)) * 0.5f;
    }
}

// =====================================================================
// Kernel 2: binarize x to fp4 nibbles + NCHW -> padded NHWC(/2B), with
// border zeroing. Grid = 32 * 58 blocks: one per (n, hp).
// xb4[n][hp][wp][128B]; byte holds channels (2c | 2c+1<<4).
// =====================================================================
__global__ __launch_bounds__(256)
void binarize_kernel(const float* __restrict__ x, unsigned char* __restrict__ xb4) {
    const int b  = blockIdx.x;
    const int n  = b / HPAD;
    const int hp = b % HPAD;
    const int t  = threadIdx.x;
    unsigned char* rowp = xb4 + ((size_t)n * HPAD + hp) * (HPAD * ROWB);

    if (hp == 0 || hp == HPAD - 1) {
        int* ip = (int*)rowp;                 // 58*128 B = 1856 ints
        for (int i = t; i < 1856; i += 256) ip[i] = 0;
        return;
    }
    const int h = hp - 1;
    __shared__ __align__(4) unsigned char tile[HWDIM * 132];  // [w][128B], pad 132
    if (t < 224) {
        const int w  = t % HWDIM;
        const int cl = t / HWDIM;             // 0..3
        const float* xp = x + (size_t)n * (CIN * SPATIAL) + (size_t)h * HWDIM + w;
        for (int c0 = cl * 2; c0 < CIN; c0 += 8) {
            float v0 = xp[(size_t)c0 * SPATIAL];
            float v1 = xp[(size_t)(c0 + 1) * SPATIAL];
            unsigned e0 = (v0 > 0.f) ? 0x2u : ((v0 < 0.f) ? 0xAu : 0x0u);
            unsigned e1 = (v1 > 0.f) ? 0x2u : ((v1 < 0.f) ? 0xAu : 0x0u);
            tile[w * 132 + (c0 >> 1)] = (unsigned char)(e0 | (e1 << 4));
        }
    }
    // zero left/right pad columns of this row
    int* ip = (int*)rowp;
    if (t < 32) ip[t] = 0;                     // w = 0
    else if (t < 64) ip[57 * 32 + (t - 32)] = 0; // w = 57
    __syncthreads();
    // drain: 8 lane-groups of 32; group g writes w = w0+g, 128B coalesced
    const int g = t >> 5, lam = t & 31;
    unsigned char* op = rowp + ROWB;           // w starts at 1
    for (int w0 = 0; w0 < HWDIM; w0 += 8) {
        int w = w0 + g;
        int val = *(const int*)&tile[w * 132 + lam * 4];
        *(int*)(op + (size_t)w * ROWB + lam * 4) = val;
    }
}

// =====================================================================
// Kernel 3: MX-fp4 implicit-GEMM via mfma_scale_f32_32x32x64_f8f6f4
// (FMT=4/fp4, scale=1.0). Block = 128(o) x 256(sp), 4 waves, each wave
// 128x64 as 4x2 tiles of 32x32. Ring-3 LDS (36KB -> 2 blocks/CU),
// homogeneous global_load_lds stream, counted vmcnt(3), 1 barrier/step.
// fp4 rows are 32B => natural layout is bank-conflict-free (slot (2r+h)&7
// covers all 8 16B-slots evenly) -> NO swizzle, pure linear staging.
// LDS traffic/CU-pair-step: 144KB (i8) -> 72KB; MFMA 1306 -> ~140 cyc.
// =====================================================================
__global__ __launch_bounds__(256, 2)
void conv_kernel(const unsigned char* __restrict__ xb4,
                 const unsigned char* __restrict__ WT4,
                 const float* __restrict__ alpha,
                 float* __restrict__ out) {
    __shared__ __align__(16) char lds[3 * LDSBUF];

    const int t    = threadIdx.x;
    const int lane = t & 63;
    const int wv   = t >> 6;

    // XCD-aware bijective remap: 784 blocks = 8 XCDs * 98
    const int bid  = blockIdx.x;
    const int tid_ = (bid & 7) * 98 + (bid >> 3);
    const int nt   = tid_ & 1;        // o-tile (0/1)
    const int mt   = tid_ >> 1;       // sp-tile (0..391)
    const int o0   = nt * 128;
    const int m0   = mt * 256;

    // ---- staging sources: thread t covers row (t>>1), 16B half (t&1) ----
    const unsigned char* w_g = WT4 + (size_t)(o0 + (t >> 1)) * WROWB + (t & 1) * 16;
    const unsigned char* a_g0;
    const unsigned char* a_g1;
    {
        int m, ni, sp, h, w;
        m = m0 + (t >> 1);
        ni = m / SPATIAL; sp = m - ni * SPATIAL; h = sp / HWDIM; w = sp - h * HWDIM;
        a_g0 = xb4 + ((size_t)(ni * HPAD + h) * HPAD + w) * ROWB + (t & 1) * 16;
        m = m0 + (t >> 1) + 128;
        ni = m / SPATIAL; sp = m - ni * SPATIAL; h = sp / HWDIM; w = sp - h * HWDIM;
        a_g1 = xb4 + ((size_t)(ni * HPAD + h) * HPAD + w) * ROWB + (t & 1) * 16;
    }
    char* dstT = lds + t * 16;        // linear LDS dest (row (t>>1), half (t&1))

    f32x16 acc[4][2];
    #pragma unroll
    for (int i = 0; i < 4; ++i)
        #pragma unroll
        for (int j = 0; j < 2; ++j)
            acc[i][j] = (f32x16){0.f,0.f,0.f,0.f,0.f,0.f,0.f,0.f,
                                 0.f,0.f,0.f,0.f,0.f,0.f,0.f,0.f};

    // ---- read-side addressing: A-lane holds row (lane&31), k-half (lane>>5)
    const int l31 = lane & 31;
    const int l5  = lane >> 5;
    const int fro = l31 * 32 + l5 * 16;   // within a 32-row x 32B tile

    #define STAGE(S, B)                                                     \
    {                                                                       \
        const int s_ = (S);                                                 \
        const int tap = s_ >> 2;                                            \
        const int kh = tap / 3, kw = tap - kh * 3;                          \
        const int aoff = (kh * HPAD + kw) * ROWB + (s_ & 3) * 32;           \
        const int woff = s_ * 32;                                           \
        char* d = dstT + (B) * LDSBUF;                                      \
        GLD16(w_g + woff, d);                                               \
        GLD16(a_g0 + aoff, d + 4096);                                       \
        GLD16(a_g1 + aoff, d + 8192);                                       \
    }

    // operand regs: data in low 4 dwords, high 4 stay 0 (fp4 uses 4 VGPRs)
    i32x8 wf[4] = {};
    i32x8 xf[2] = {};

    // prologue: stage 0,1 (6 loads); drain stage 0 (3 younger); barrier
    STAGE(0, 0);
    STAGE(1, 1);
    asm volatile("s_waitcnt vmcnt(3)\n\ts_barrier" ::: "memory");

    #pragma unroll
    for (int s = 0; s < NSTEP; ++s) {
        const char* Wb = lds + (s % 3) * LDSBUF;

        if (s + 2 < NSTEP) STAGE(s + 2, (s + 2) % 3);   // 3 vmem DMA

        #pragma unroll
        for (int i = 0; i < 4; ++i)
            *(i32x4*)&wf[i] = *(const i32x4*)(Wb + i * 1024 + fro);
        #pragma unroll
        for (int j = 0; j < 2; ++j)
            *(i32x4*)&xf[j] = *(const i32x4*)(Wb + 4096 + wv * 2048 + j * 1024 + fro);

        __builtin_amdgcn_s_setprio(1);
        #pragma unroll
        for (int i = 0; i < 4; ++i)
            #pragma unroll
            for (int j = 0; j < 2; ++j)
                acc[i][j] = __builtin_amdgcn_mfma_scale_f32_32x32x64_f8f6f4(
                    wf[i], xf[j], acc[i][j], 4, 4, 0, 127, 0, 127);
        __builtin_amdgcn_s_setprio(0);

        // end-of-step: stage s+1 retired (3 younger DMA), reads drained, barrier
        if (s < NSTEP - 2)
            asm volatile("s_waitcnt vmcnt(3) lgkmcnt(0)\n\ts_barrier" ::: "memory");
        else if (s == NSTEP - 2)
            asm volatile("s_waitcnt vmcnt(0) lgkmcnt(0)\n\ts_barrier" ::: "memory");
    }

    // ---- epilogue: out[n][o][h][w] = acc * alpha[o] ----
    // 32x32 D frag: col(sp) = lane&31, row(o) = (reg&3)+8*(reg>>2)+4*(lane>>5)
    #pragma unroll
    for (int j = 0; j < 2; ++j) {
        int m  = m0 + wv * 64 + j * 32 + l31;
        int ni = m / SPATIAL;
        int sp = m - ni * SPATIAL;
        long base = (long)ni * (OCH * SPATIAL) + sp;
        #pragma unroll
        for (int i = 0; i < 4; ++i) {
            #pragma unroll
            for (int r = 0; r < 16; ++r) {
                int o = o0 + i * 32 + (r & 3) + 8 * (r >> 2) + 4 * l5;
                out[base + (long)o * SPATIAL] = acc[i][j][r] * alpha[o];
            }
        }
    }
    #undef STAGE
}

// =====================================================================
extern "C" void kernel_launch(void* const* d_in, const int* in_sizes, int n_in,
                              void* d_out, int out_size, void* d_ws, size_t ws_size,
                              hipStream_t stream) {
    const float* x  = (const float*)d_in[0];
    const float* w1 = (const float*)d_in[1];
    const float* w2 = (const float*)d_in[2];
    float* out = (float*)d_out;

    char* ws = (char*)d_ws;
    unsigned char* xb4   = (unsigned char*)ws;
    unsigned char* WT4   = (unsigned char*)(ws + WT4_OFF);
    float*         alpha = (float*)(ws + ALPHA_OFF);

    hipLaunchKernelGGL(prep_weights, dim3(OCH), dim3(256), 0, stream, w1, w2, WT4, alpha);
    hipLaunchKernelGGL(binarize_kernel, dim3(NIMG * HPAD), dim3(256), 0, stream, x, xb4);
    hipLaunchKernelGGL(conv_kernel, dim3(M_TOT / 128), dim3(256), 0, stream,
                       xb4, WT4, alpha, out);
}